// Round 1
// baseline (576.901 us; speedup 1.0000x reference)
//
#include <hip/hip_runtime.h>
#include <stdint.h>

// Shapes fixed by the problem: B=4,H=16 -> BH=64; S=1024; D=64.
// d_ws layout (needs 28 MB):
//   [0,8M)    Qb  bf16 [bh][s][d]  (pre-scaled by 1/8)
//   [8M,16M)  Kb  bf16 [bh][s][d]
//   [16M,24M) Vt  bf16 [bh][d][s]  (V transposed)
//   [24M,28M) Mb  u8   [b][q][k]   (mask canonicalized to bytes)

#define S_LEN 1024
#define D_DIM 64
#define QT 16
#define NEG_FILL (-1000000000.0f)
#define LOG2E 1.44269504088896340736f

typedef __bf16 bf16x8 __attribute__((ext_vector_type(8)));
typedef float f32x4 __attribute__((ext_vector_type(4)));
typedef unsigned short u16x4 __attribute__((ext_vector_type(4)));

__device__ __forceinline__ unsigned short f2bf(float x) {
    unsigned u = __builtin_bit_cast(unsigned, x);
    u += 0x7fffu + ((u >> 16) & 1u);
    return (unsigned short)(u >> 16);
}
__device__ __forceinline__ float bf2f(unsigned short b) {
    return __builtin_bit_cast(float, (unsigned)b << 16);
}

// Swizzled LDS addressing for the 16x1024 u16 score block: 2048 B rows,
// XOR a 16B-granular row-dependent swizzle into the byte offset. This
// replaces the old +8-u16 row pad (33 KB) with exactly 32 KB -> 5 wg/CU.
// All accesses (b16 scatter write, 8B row reads/writes, 16B fragment reads)
// stay naturally aligned because the XOR operand is a multiple of 16.
__device__ __forceinline__ unsigned short* sptr(unsigned short* s, int row, int col) {
    return (unsigned short*)((char*)s + row * 2048 + ((col * 2) ^ ((row & 7) << 4)));
}

// ---- prep: q,k -> bf16 (q pre-scaled) + mask -> bytes, fused -------------
__global__ void prep_qkm(const float* __restrict__ q, const float* __restrict__ k,
                         const void* __restrict__ mraw,
                         unsigned short* __restrict__ Qb, unsigned short* __restrict__ Kb,
                         unsigned char* __restrict__ Mb)
{
    const int t = threadIdx.x;
    const int i = blockIdx.x * 256 + t;           // float4 / uchar4 index, 1,048,576 total
    f32x4 q4 = ((const f32x4*)q)[i];
    f32x4 k4 = ((const f32x4*)k)[i];
    u16x4 qo, ko;
#pragma unroll
    for (int j = 0; j < 4; ++j) {
        qo[j] = f2bf(q4[j] * 0.125f);
        ko[j] = f2bf(k4[j]);
    }
    ((u16x4*)Qb)[i] = qo;
    ((u16x4*)Kb)[i] = ko;

    // mask format detect (cheap, L2-broadcast) then canonicalize 4 elements
    __shared__ int s_not_int, s_not_f32;
    if (t == 0) { s_not_int = 0; s_not_f32 = 0; }
    __syncthreads();
    const unsigned* wdd = (const unsigned*)mraw;
    int ni = 0, nf = 0;
    for (int j = t; j < 1024; j += 256) {
        unsigned x = wdd[j];
        if (x > 1u) ni = 1;
        if (x != 0u && x != 0x3f800000u) nf = 1;
    }
    if (ni) s_not_int = 1;
    if (nf) s_not_f32 = 1;
    __syncthreads();
    const int fmt = (s_not_int == 0) ? 0 : ((s_not_f32 == 0) ? 1 : 2);
    uchar4 o;
    if (fmt == 0) {        // int32 0/1
        int4 x = ((const int4*)mraw)[i];
        o.x = x.x ? 1 : 0; o.y = x.y ? 1 : 0; o.z = x.z ? 1 : 0; o.w = x.w ? 1 : 0;
    } else if (fmt == 1) { // fp32 0.0/1.0
        float4 x = ((const float4*)mraw)[i];
        o.x = (x.x != 0.f) ? 1 : 0; o.y = (x.y != 0.f) ? 1 : 0;
        o.z = (x.z != 0.f) ? 1 : 0; o.w = (x.w != 0.f) ? 1 : 0;
    } else {               // bool bytes
        uchar4 x = ((const uchar4*)mraw)[i];
        o.x = x.x ? 1 : 0; o.y = x.y ? 1 : 0; o.z = x.z ? 1 : 0; o.w = x.w ? 1 : 0;
    }
    ((uchar4*)Mb)[i] = o;
}

// ---- prep: V -> V^T bf16 (64x64 tiles through LDS) -----------------------
__global__ void prep_vt(const float* __restrict__ v, unsigned short* __restrict__ Vt)
{
    __shared__ unsigned short sT[64 * 72];
    const int bh = blockIdx.x >> 4;
    const int st = blockIdx.x & 15;
    const int t = threadIdx.x;
    const float* vb = v + (size_t)(bh * S_LEN + st * 64) * D_DIM;
#pragma unroll
    for (int p = 0; p < 4; ++p) {
        int lin = p * 256 + t;
        int r = lin >> 4;
        int c = lin & 15;
        f32x4 x = ((const f32x4*)(vb + r * D_DIM))[c];
        unsigned short* dst = &sT[r * 72 + c * 4];
#pragma unroll
        for (int j = 0; j < 4; ++j) dst[j] = f2bf(x[j]);
    }
    __syncthreads();
    unsigned short* ob = Vt + (size_t)bh * D_DIM * S_LEN + st * 64;
#pragma unroll
    for (int p = 0; p < 4; ++p) {
        int lin = p * 256 + t;
        int d = lin >> 4;
        int s4 = (lin & 15) * 4;
        u16x4 o;
#pragma unroll
        for (int j = 0; j < 4; ++j) o[j] = sT[(s4 + j) * 72 + d];
        *(u16x4*)&ob[d * S_LEN + s4] = o;
    }
}

// ---- main: scores -> softmax -> attn write + PV --------------------------
// Latency-bound fixes this round:
//  * LDS 33 KB -> 32 KB (XOR swizzle instead of row pad) => 5 wg/CU.
//  * Phase-2 row software pipeline: sim loads for row r+1 issue before
//    row r's softmax chain; row 0's loads issue BEFORE the phase-1 barrier.
//  * Phase-1/3 K/V fragment prefetch one kt ahead; first V fragment issues
//    before the phase-2 barrier.
//  * Nontemporal sim loads + attn/out stores: 512 MB of streaming traffic
//    stops evicting the L2-resident K/V/Q/mask working set.
__global__ __launch_bounds__(256, 5)
void attn_main(const float* __restrict__ simg_, const unsigned short* __restrict__ Qb,
               const unsigned short* __restrict__ Kb, const unsigned short* __restrict__ Vtb,
               const unsigned char* __restrict__ Mb, float* __restrict__ out,
               float* __restrict__ attn)
{
    __shared__ __align__(16) unsigned short sS[QT * S_LEN];   // 32768 B exactly

    const int blk = blockIdx.x;
    const int bh = blk >> 6;
    const int qt = blk & 63;
    const int b = bh >> 4;
    const int t = threadIdx.x;
    const int w = t >> 6;
    const int lane = t & 63;
    const int quad = lane >> 4;
    const int l15 = lane & 15;

    const unsigned short* Qg = Qb + (size_t)(bh * S_LEN + qt * QT) * D_DIM;
    const unsigned short* Kg = Kb + (size_t)bh * S_LEN * D_DIM;
    const unsigned short* Vg = Vtb + (size_t)bh * D_DIM * S_LEN;
    const float* simg = simg_ + ((size_t)(bh * S_LEN + qt * QT)) * S_LEN;
    const unsigned char* mg = Mb + ((size_t)(b * S_LEN + qt * QT)) * S_LEN;
    float* attng = attn + ((size_t)(bh * S_LEN + qt * QT)) * S_LEN;

    // ---- phase 1: raw scores = (q/8)@k^T, park bf16 in LDS. No barriers.
    const int n0 = w * 16;
    const bf16x8 av0 = *(const bf16x8*)&Qg[l15 * D_DIM + quad * 8];
    const bf16x8 av1 = *(const bf16x8*)&Qg[l15 * D_DIM + 32 + quad * 8];
    const unsigned short* kp0 = &Kg[(size_t)(n0 + l15) * D_DIM + quad * 8];
    bf16x8 kb0 = *(const bf16x8*)kp0;
    bf16x8 kb1 = *(const bf16x8*)(kp0 + 32);
#pragma unroll 4
    for (int kt = 0; kt < 16; ++kt) {
        bf16x8 bv0 = kb0, bv1 = kb1;
        if (kt < 15) {   // prefetch next kt's K fragment (uniform branch)
            const unsigned short* kp = &Kg[(size_t)((kt + 1) * 64 + n0 + l15) * D_DIM + quad * 8];
            kb0 = *(const bf16x8*)kp;
            kb1 = *(const bf16x8*)(kp + 32);
        }
        f32x4 acc = {0.f, 0.f, 0.f, 0.f};
        acc = __builtin_amdgcn_mfma_f32_16x16x32_bf16(av0, bv0, acc, 0, 0, 0);
        acc = __builtin_amdgcn_mfma_f32_16x16x32_bf16(av1, bv1, acc, 0, 0, 0);
        const int colg = kt * 64 + n0 + l15;
#pragma unroll
        for (int r = 0; r < 4; ++r)
            *sptr(sS, quad * 4 + r, colg) = f2bf(acc[r]);
    }

    // Prefetch this wave's row-0 sim before the barrier (global, no LDS dep):
    // the ~900cy HBM latency overlaps the barrier drain + other waves' phase 1.
    const float* sp_w = simg + (size_t)(w * 4) * S_LEN;
    f32x4 svb[2][4];
#pragma unroll
    for (int j = 0; j < 4; ++j)
        svb[0][j] = __builtin_nontemporal_load((const f32x4*)&sp_w[j * 256 + lane * 4]);
    __syncthreads();

    // ---- phase 2: mask + similarity + exact softmax, software-pipelined
    //      over the wave's 4 rows. Write attn fp32 (nt), rewrite probs bf16.
#pragma unroll
    for (int rr = 0; rr < 4; ++rr) {
        const int cb = rr & 1;
        const int row = w * 4 + rr;
        if (rr < 3) {    // issue next row's sim loads before this row's chain
            const float* spn = sp_w + (size_t)(rr + 1) * S_LEN;
#pragma unroll
            for (int j = 0; j < 4; ++j)
                svb[cb ^ 1][j] = __builtin_nontemporal_load((const f32x4*)&spn[j * 256 + lane * 4]);
        }
        const unsigned char* mp = mg + (size_t)row * S_LEN;
        float vals[16];
        float mx = -3.0e38f;
#pragma unroll
        for (int j = 0; j < 4; ++j) {
            const int col = j * 256 + lane * 4;
            u16x4 x = *(const u16x4*)sptr(sS, row, col);
            uchar4 mk = *(const uchar4*)&mp[col];
            f32x4 sv = svb[cb][j];
            float f0 = mk.x ? NEG_FILL : (bf2f(x[0]) + sv[0]);
            float f1 = mk.y ? NEG_FILL : (bf2f(x[1]) + sv[1]);
            float f2 = mk.z ? NEG_FILL : (bf2f(x[2]) + sv[2]);
            float f3 = mk.w ? NEG_FILL : (bf2f(x[3]) + sv[3]);
            vals[j * 4 + 0] = f0; vals[j * 4 + 1] = f1;
            vals[j * 4 + 2] = f2; vals[j * 4 + 3] = f3;
            mx = fmaxf(mx, fmaxf(fmaxf(f0, f1), fmaxf(f2, f3)));
        }
#pragma unroll
        for (int off = 32; off > 0; off >>= 1)
            mx = fmaxf(mx, __shfl_xor(mx, off, 64));
        float sum = 0.f;
#pragma unroll
        for (int i = 0; i < 16; ++i) {
            float e = __builtin_amdgcn_exp2f((vals[i] - mx) * LOG2E);
            vals[i] = e;
            sum += e;
        }
#pragma unroll
        for (int off = 32; off > 0; off >>= 1)
            sum += __shfl_xor(sum, off, 64);
        const float rinv = 1.0f / sum;
#pragma unroll
        for (int j = 0; j < 4; ++j) {
            const int col = j * 256 + lane * 4;
            f32x4 p;
            u16x4 pb;
#pragma unroll
            for (int i = 0; i < 4; ++i) {
                float pi = vals[j * 4 + i] * rinv;
                p[i] = pi;
                pb[i] = f2bf(pi);
            }
            __builtin_nontemporal_store(p, (f32x4*)&attng[(size_t)row * S_LEN + col]);
            *(u16x4*)sptr(sS, row, col) = pb;
        }
    }

    // Prefetch phase-3's first V fragment before the barrier (global, no LDS dep).
    const int d0 = w * 16;
    const unsigned short* vpp = &Vg[(size_t)(d0 + l15) * S_LEN + quad * 8];
    bf16x8 vb0 = *(const bf16x8*)vpp;
    bf16x8 vb1 = *(const bf16x8*)(vpp + 32);
    __syncthreads();

    // ---- phase 3: out = P @ V. A from LDS probs, B direct from Vt global.
    f32x4 oacc = {0.f, 0.f, 0.f, 0.f};
#pragma unroll 4
    for (int kt = 0; kt < 16; ++kt) {
        bf16x8 bv0 = vb0, bv1 = vb1;
        if (kt < 15) {   // prefetch next kt's V fragment
            const unsigned short* vp = &Vg[(size_t)(d0 + l15) * S_LEN + (kt + 1) * 64 + quad * 8];
            vb0 = *(const bf16x8*)vp;
            vb1 = *(const bf16x8*)(vp + 32);
        }
        bf16x8 pa0 = *(const bf16x8*)sptr(sS, l15, kt * 64 + quad * 8);
        bf16x8 pa1 = *(const bf16x8*)sptr(sS, l15, kt * 64 + 32 + quad * 8);
        oacc = __builtin_amdgcn_mfma_f32_16x16x32_bf16(pa0, bv0, oacc, 0, 0, 0);
        oacc = __builtin_amdgcn_mfma_f32_16x16x32_bf16(pa1, bv1, oacc, 0, 0, 0);
    }
    float* og = out + ((size_t)(bh * S_LEN + qt * QT)) * D_DIM;
#pragma unroll
    for (int r = 0; r < 4; ++r) {
        const int row = quad * 4 + r;
        __builtin_nontemporal_store(oacc[r], &og[row * D_DIM + d0 + l15]);
    }
}

extern "C" void kernel_launch(void* const* d_in, const int* in_sizes, int n_in,
                              void* d_out, int out_size, void* d_ws, size_t ws_size,
                              hipStream_t stream)
{
    const float* q = (const float*)d_in[0];
    const float* k = (const float*)d_in[1];
    const float* v = (const float*)d_in[2];
    const float* sim = (const float*)d_in[3];
    const void* mask = d_in[4];
    float* out = (float*)d_out;
    float* attn = out + (size_t)4 * 16 * 1024 * 64;   // output first, then attn

    char* ws = (char*)d_ws;                           // needs 28 MB
    unsigned short* Qb = (unsigned short*)(ws + (size_t)0);
    unsigned short* Kb = (unsigned short*)(ws + ((size_t)8 << 20));
    unsigned short* Vt = (unsigned short*)(ws + ((size_t)16 << 20));
    unsigned char*  Mb = (unsigned char*)(ws + ((size_t)24 << 20));

    prep_qkm<<<4096, 256, 0, stream>>>(q, k, mask, Qb, Kb, Mb);
    prep_vt<<<1024, 256, 0, stream>>>(v, Vt);
    attn_main<<<4096, 256, 0, stream>>>(sim, Qb, Kb, Vt, Mb, out, attn);
}

// Round 3
// 570.492 us; speedup vs baseline: 1.0112x; 1.0112x over previous
//
#include <hip/hip_runtime.h>
#include <stdint.h>

// Shapes fixed by the problem: B=4,H=16 -> BH=64; S=1024; D=64.
// d_ws layout (needs 28 MB):
//   [0,8M)    Qb  bf16 [bh][s][d]  (pre-scaled by 1/8)
//   [8M,16M)  Kb  bf16 [bh][s][d]
//   [16M,24M) Vt  bf16 [bh][d][s]  (V transposed)
//   [24M,28M) Mb  u8   [b][q][k]   (mask canonicalized to bytes)

#define S_LEN 1024
#define D_DIM 64
#define QT 16
#define NEG_FILL (-1000000000.0f)
#define LOG2E 1.44269504088896340736f

typedef __bf16 bf16x8 __attribute__((ext_vector_type(8)));
typedef float f32x4 __attribute__((ext_vector_type(4)));
typedef unsigned short u16x4 __attribute__((ext_vector_type(4)));

__device__ __forceinline__ unsigned short f2bf(float x) {
    unsigned u = __builtin_bit_cast(unsigned, x);
    u += 0x7fffu + ((u >> 16) & 1u);
    return (unsigned short)(u >> 16);
}
__device__ __forceinline__ float bf2f(unsigned short b) {
    return __builtin_bit_cast(float, (unsigned)b << 16);
}

// Swizzled LDS addressing for the 16x1024 u16 score block: 2048 B rows,
// XOR a 16B-granular row-dependent swizzle into the byte offset (32 KB
// exactly; no pad). XOR operand multiple of 16 -> all 2/8/16B accesses
// stay naturally aligned.
__device__ __forceinline__ unsigned short* sptr(unsigned short* s, int row, int col) {
    return (unsigned short*)((char*)s + row * 2048 + ((col * 2) ^ ((row & 7) << 4)));
}

// ---- prep: q,k -> bf16 (q pre-scaled) + mask -> bytes, fused -------------
__global__ void prep_qkm(const float* __restrict__ q, const float* __restrict__ k,
                         const void* __restrict__ mraw,
                         unsigned short* __restrict__ Qb, unsigned short* __restrict__ Kb,
                         unsigned char* __restrict__ Mb)
{
    const int t = threadIdx.x;
    const int i = blockIdx.x * 256 + t;           // float4 / uchar4 index, 1,048,576 total
    f32x4 q4 = ((const f32x4*)q)[i];
    f32x4 k4 = ((const f32x4*)k)[i];
    u16x4 qo, ko;
#pragma unroll
    for (int j = 0; j < 4; ++j) {
        qo[j] = f2bf(q4[j] * 0.125f);
        ko[j] = f2bf(k4[j]);
    }
    ((u16x4*)Qb)[i] = qo;
    ((u16x4*)Kb)[i] = ko;

    // mask format detect (cheap, L2-broadcast) then canonicalize 4 elements
    __shared__ int s_not_int, s_not_f32;
    if (t == 0) { s_not_int = 0; s_not_f32 = 0; }
    __syncthreads();
    const unsigned* wdd = (const unsigned*)mraw;
    int ni = 0, nf = 0;
    for (int j = t; j < 1024; j += 256) {
        unsigned x = wdd[j];
        if (x > 1u) ni = 1;
        if (x != 0u && x != 0x3f800000u) nf = 1;
    }
    if (ni) s_not_int = 1;
    if (nf) s_not_f32 = 1;
    __syncthreads();
    const int fmt = (s_not_int == 0) ? 0 : ((s_not_f32 == 0) ? 1 : 2);
    uchar4 o;
    if (fmt == 0) {        // int32 0/1
        int4 x = ((const int4*)mraw)[i];
        o.x = x.x ? 1 : 0; o.y = x.y ? 1 : 0; o.z = x.z ? 1 : 0; o.w = x.w ? 1 : 0;
    } else if (fmt == 1) { // fp32 0.0/1.0
        float4 x = ((const float4*)mraw)[i];
        o.x = (x.x != 0.f) ? 1 : 0; o.y = (x.y != 0.f) ? 1 : 0;
        o.z = (x.z != 0.f) ? 1 : 0; o.w = (x.w != 0.f) ? 1 : 0;
    } else {               // bool bytes
        uchar4 x = ((const uchar4*)mraw)[i];
        o.x = x.x ? 1 : 0; o.y = x.y ? 1 : 0; o.z = x.z ? 1 : 0; o.w = x.w ? 1 : 0;
    }
    ((uchar4*)Mb)[i] = o;
}

// ---- prep: V -> V^T bf16 (64x64 tiles through LDS) -----------------------
__global__ void prep_vt(const float* __restrict__ v, unsigned short* __restrict__ Vt)
{
    __shared__ unsigned short sT[64 * 72];
    const int bh = blockIdx.x >> 4;
    const int st = blockIdx.x & 15;
    const int t = threadIdx.x;
    const float* vb = v + (size_t)(bh * S_LEN + st * 64) * D_DIM;
#pragma unroll
    for (int p = 0; p < 4; ++p) {
        int lin = p * 256 + t;
        int r = lin >> 4;
        int c = lin & 15;
        f32x4 x = ((const f32x4*)(vb + r * D_DIM))[c];
        unsigned short* dst = &sT[r * 72 + c * 4];
#pragma unroll
        for (int j = 0; j < 4; ++j) dst[j] = f2bf(x[j]);
    }
    __syncthreads();
    unsigned short* ob = Vt + (size_t)bh * D_DIM * S_LEN + st * 64;
#pragma unroll
    for (int p = 0; p < 4; ++p) {
        int lin = p * 256 + t;
        int d = lin >> 4;
        int s4 = (lin & 15) * 4;
        u16x4 o;
#pragma unroll
        for (int j = 0; j < 4; ++j) o[j] = sT[(s4 + j) * 72 + d];
        *(u16x4*)&ob[d * S_LEN + s4] = o;
    }
}

// ---- 2-row interleaved masked softmax (ILP=2 on the reduce chains) -------
__device__ __forceinline__ void softmax2(
    unsigned short* sS, const int row0, const int lane,
    f32x4 (&v0)[4], f32x4 (&v1)[4],
    uchar4 (&k0)[4], uchar4 (&k1)[4],
    float* __restrict__ a0, float* __restrict__ a1)
{
    u16x4 x0[4], x1[4];
#pragma unroll
    for (int j = 0; j < 4; ++j) {
        const int col = j * 256 + lane * 4;
        x0[j] = *(const u16x4*)sptr(sS, row0, col);
        x1[j] = *(const u16x4*)sptr(sS, row0 + 1, col);
    }
    float mx0 = -3.0e38f, mx1 = -3.0e38f;
#pragma unroll
    for (int j = 0; j < 4; ++j) {
        f32x4 a = v0[j], b = v1[j];
        const uchar4 ka = k0[j], kb = k1[j];
        a[0] = ka.x ? NEG_FILL : (bf2f(x0[j][0]) + a[0]);
        a[1] = ka.y ? NEG_FILL : (bf2f(x0[j][1]) + a[1]);
        a[2] = ka.z ? NEG_FILL : (bf2f(x0[j][2]) + a[2]);
        a[3] = ka.w ? NEG_FILL : (bf2f(x0[j][3]) + a[3]);
        b[0] = kb.x ? NEG_FILL : (bf2f(x1[j][0]) + b[0]);
        b[1] = kb.y ? NEG_FILL : (bf2f(x1[j][1]) + b[1]);
        b[2] = kb.z ? NEG_FILL : (bf2f(x1[j][2]) + b[2]);
        b[3] = kb.w ? NEG_FILL : (bf2f(x1[j][3]) + b[3]);
        v0[j] = a; v1[j] = b;
        mx0 = fmaxf(mx0, fmaxf(fmaxf(a[0], a[1]), fmaxf(a[2], a[3])));
        mx1 = fmaxf(mx1, fmaxf(fmaxf(b[0], b[1]), fmaxf(b[2], b[3])));
    }
#pragma unroll
    for (int off = 32; off > 0; off >>= 1) {
        mx0 = fmaxf(mx0, __shfl_xor(mx0, off, 64));
        mx1 = fmaxf(mx1, __shfl_xor(mx1, off, 64));
    }
    float s0 = 0.f, s1 = 0.f;
#pragma unroll
    for (int j = 0; j < 4; ++j) {
        f32x4 a = v0[j], b = v1[j];
#pragma unroll
        for (int i = 0; i < 4; ++i) {
            a[i] = __builtin_amdgcn_exp2f((a[i] - mx0) * LOG2E);
            b[i] = __builtin_amdgcn_exp2f((b[i] - mx1) * LOG2E);
            s0 += a[i];
            s1 += b[i];
        }
        v0[j] = a; v1[j] = b;
    }
#pragma unroll
    for (int off = 32; off > 0; off >>= 1) {
        s0 += __shfl_xor(s0, off, 64);
        s1 += __shfl_xor(s1, off, 64);
    }
    const float r0 = 1.0f / s0, r1 = 1.0f / s1;
#pragma unroll
    for (int j = 0; j < 4; ++j) {
        const int col = j * 256 + lane * 4;
        f32x4 p0 = v0[j] * r0, p1 = v1[j] * r1;
        u16x4 q0, q1;
#pragma unroll
        for (int i = 0; i < 4; ++i) { q0[i] = f2bf(p0[i]); q1[i] = f2bf(p1[i]); }
        __builtin_nontemporal_store(p0, (f32x4*)(a0 + col));
        __builtin_nontemporal_store(p1, (f32x4*)(a1 + col));
        *(u16x4*)sptr(sS, row0, col) = q0;
        *(u16x4*)sptr(sS, row0 + 1, col) = q1;
    }
}

// ---- main: scores -> softmax -> attn write + PV --------------------------
// (1) XCD-contiguous block swizzle so each bh's 64 blocks live on ONE XCD
//     -> K/V truly L2-resident (0.6 MB/XCD vs 5 MB thrash).
// (2) 4-deep rotating K/V fragment prefetch + pair-batched sim/mask
//     prefetch, pinned with sched_barrier(0) so the backend cannot sink
//     the loads (round-1 failure: VGPR=48 proved the pipeline was
//     register-minimized away).
// (3) launch_bounds(256,4) -> VGPR cap 128 so buffers stay in registers.
__global__ __launch_bounds__(256, 4)
void attn_main(const float* __restrict__ simg_, const unsigned short* __restrict__ Qb,
               const unsigned short* __restrict__ Kb, const unsigned short* __restrict__ Vtb,
               const unsigned char* __restrict__ Mb, float* __restrict__ out,
               float* __restrict__ attn)
{
    __shared__ __align__(16) unsigned short sS[QT * S_LEN];   // 32768 B exactly

    const int blk = ((blockIdx.x & 7) << 9) | (blockIdx.x >> 3);  // XCD-contiguous
    const int bh = blk >> 6;
    const int qt = blk & 63;
    const int b = bh >> 4;
    const int t = threadIdx.x;
    const int w = t >> 6;
    const int lane = t & 63;
    const int quad = lane >> 4;
    const int l15 = lane & 15;

    const unsigned short* Qg = Qb + (size_t)(bh * S_LEN + qt * QT) * D_DIM;
    const unsigned short* Kg = Kb + (size_t)bh * S_LEN * D_DIM;
    const unsigned short* Vg = Vtb + (size_t)bh * D_DIM * S_LEN;
    const float* simg = simg_ + ((size_t)(bh * S_LEN + qt * QT)) * S_LEN;
    const unsigned char* mg = Mb + ((size_t)(b * S_LEN + qt * QT)) * S_LEN;
    float* attng = attn + ((size_t)(bh * S_LEN + qt * QT)) * S_LEN;

    // ---- phase 1: raw scores = (q/8)@k^T, park bf16 in LDS. No barriers.
    const int n0 = w * 16;
    const bf16x8 av0 = *(const bf16x8*)&Qg[l15 * D_DIM + quad * 8];
    const bf16x8 av1 = *(const bf16x8*)&Qg[l15 * D_DIM + 32 + quad * 8];
    const unsigned short* kfrag = Kg + (size_t)(n0 + l15) * D_DIM + quad * 8;

#define SB __builtin_amdgcn_sched_barrier(0)
#define LOADK(D0, D1, KT) do { \
    const unsigned short* _p = kfrag + (size_t)(KT) * 4096; \
    D0 = *(const bf16x8*)_p; D1 = *(const bf16x8*)(_p + 32); } while (0)
#define QKSTEP(F0, F1, KT) do { \
    f32x4 _acc = {0.f, 0.f, 0.f, 0.f}; \
    _acc = __builtin_amdgcn_mfma_f32_16x16x32_bf16(av0, F0, _acc, 0, 0, 0); \
    _acc = __builtin_amdgcn_mfma_f32_16x16x32_bf16(av1, F1, _acc, 0, 0, 0); \
    const int _cg = (KT) * 64 + n0 + l15; \
    *sptr(sS, quad * 4 + 0, _cg) = f2bf(_acc[0]); \
    *sptr(sS, quad * 4 + 1, _cg) = f2bf(_acc[1]); \
    *sptr(sS, quad * 4 + 2, _cg) = f2bf(_acc[2]); \
    *sptr(sS, quad * 4 + 3, _cg) = f2bf(_acc[3]); } while (0)

    {
        bf16x8 ka0, ka1, kb0, kb1, kc0, kc1, kd0, kd1;
        LOADK(ka0, ka1, 0); LOADK(kb0, kb1, 1); LOADK(kc0, kc1, 2); LOADK(kd0, kd1, 3);
        SB;
        QKSTEP(ka0, ka1, 0);  LOADK(ka0, ka1, 4);  SB;
        QKSTEP(kb0, kb1, 1);  LOADK(kb0, kb1, 5);  SB;
        QKSTEP(kc0, kc1, 2);  LOADK(kc0, kc1, 6);  SB;
        QKSTEP(kd0, kd1, 3);  LOADK(kd0, kd1, 7);  SB;
        QKSTEP(ka0, ka1, 4);  LOADK(ka0, ka1, 8);  SB;
        QKSTEP(kb0, kb1, 5);  LOADK(kb0, kb1, 9);  SB;
        QKSTEP(kc0, kc1, 6);  LOADK(kc0, kc1, 10); SB;
        QKSTEP(kd0, kd1, 7);  LOADK(kd0, kd1, 11); SB;
        QKSTEP(ka0, ka1, 8);  LOADK(ka0, ka1, 12); SB;
        QKSTEP(kb0, kb1, 9);  LOADK(kb0, kb1, 13); SB;
        QKSTEP(kc0, kc1, 10); LOADK(kc0, kc1, 14); SB;
        QKSTEP(kd0, kd1, 11); LOADK(kd0, kd1, 15); SB;
        QKSTEP(ka0, ka1, 12);
        QKSTEP(kb0, kb1, 13);
        QKSTEP(kc0, kc1, 14);
        QKSTEP(kd0, kd1, 15);
    }

    // Prefetch pair-0 (rows w*4, w*4+1) sim + mask before the barrier:
    // HBM latency overlaps the barrier drain + other waves' phase-1 tails.
    const float* sp_w = simg + (size_t)(w * 4) * S_LEN;
    const unsigned char* mp_w = mg + (size_t)(w * 4) * S_LEN;
    f32x4 sA[4], sB[4], sC[4], sD[4];
    uchar4 mA[4], mB[4], mC[4], mD[4];
#pragma unroll
    for (int j = 0; j < 4; ++j) {
        const int col = j * 256 + lane * 4;
        sA[j] = __builtin_nontemporal_load((const f32x4*)&sp_w[col]);
        sB[j] = __builtin_nontemporal_load((const f32x4*)&sp_w[S_LEN + col]);
        mA[j] = *(const uchar4*)&mp_w[col];
        mB[j] = *(const uchar4*)&mp_w[S_LEN + col];
    }
    SB;
    __syncthreads();

    // ---- phase 2: pair 0 (prefetch pair 1 first, pinned), then pair 1.
#pragma unroll
    for (int j = 0; j < 4; ++j) {
        const int col = j * 256 + lane * 4;
        sC[j] = __builtin_nontemporal_load((const f32x4*)&sp_w[2 * S_LEN + col]);
        sD[j] = __builtin_nontemporal_load((const f32x4*)&sp_w[3 * S_LEN + col]);
        mC[j] = *(const uchar4*)&mp_w[2 * S_LEN + col];
        mD[j] = *(const uchar4*)&mp_w[3 * S_LEN + col];
    }
    SB;
    softmax2(sS, w * 4 + 0, lane, sA, sB, mA, mB,
             attng + (size_t)(w * 4 + 0) * S_LEN, attng + (size_t)(w * 4 + 1) * S_LEN);
    softmax2(sS, w * 4 + 2, lane, sC, sD, mC, mD,
             attng + (size_t)(w * 4 + 2) * S_LEN, attng + (size_t)(w * 4 + 3) * S_LEN);

    // Prefetch phase-3's first 4 V fragments before the barrier.
    const int d0 = w * 16;
    const unsigned short* vfrag = Vg + (size_t)(d0 + l15) * S_LEN + quad * 8;

#define LOADV(D0, D1, KT) do { \
    const unsigned short* _p = vfrag + (KT) * 64; \
    D0 = *(const bf16x8*)_p; D1 = *(const bf16x8*)(_p + 32); } while (0)
#define PVSTEP(F0, F1, KT) do { \
    bf16x8 _pa0 = *(const bf16x8*)sptr(sS, l15, (KT) * 64 + quad * 8); \
    bf16x8 _pa1 = *(const bf16x8*)sptr(sS, l15, (KT) * 64 + 32 + quad * 8); \
    oacc = __builtin_amdgcn_mfma_f32_16x16x32_bf16(_pa0, F0, oacc, 0, 0, 0); \
    oacc = __builtin_amdgcn_mfma_f32_16x16x32_bf16(_pa1, F1, oacc, 0, 0, 0); } while (0)

    bf16x8 va0, va1, vb0, vb1, vc0, vc1, vd0, vd1;
    LOADV(va0, va1, 0); LOADV(vb0, vb1, 1); LOADV(vc0, vc1, 2); LOADV(vd0, vd1, 3);
    SB;
    __syncthreads();

    // ---- phase 3: out = P @ V. A from LDS probs, B direct from Vt (L2).
    f32x4 oacc = {0.f, 0.f, 0.f, 0.f};
    PVSTEP(va0, va1, 0);  LOADV(va0, va1, 4);  SB;
    PVSTEP(vb0, vb1, 1);  LOADV(vb0, vb1, 5);  SB;
    PVSTEP(vc0, vc1, 2);  LOADV(vc0, vc1, 6);  SB;
    PVSTEP(vd0, vd1, 3);  LOADV(vd0, vd1, 7);  SB;
    PVSTEP(va0, va1, 4);  LOADV(va0, va1, 8);  SB;
    PVSTEP(vb0, vb1, 5);  LOADV(vb0, vb1, 9);  SB;
    PVSTEP(vc0, vc1, 6);  LOADV(vc0, vc1, 10); SB;
    PVSTEP(vd0, vd1, 7);  LOADV(vd0, vd1, 11); SB;
    PVSTEP(va0, va1, 8);  LOADV(va0, va1, 12); SB;
    PVSTEP(vb0, vb1, 9);  LOADV(vb0, vb1, 13); SB;
    PVSTEP(vc0, vc1, 10); LOADV(vc0, vc1, 14); SB;
    PVSTEP(vd0, vd1, 11); LOADV(vd0, vd1, 15); SB;
    PVSTEP(va0, va1, 12);
    PVSTEP(vb0, vb1, 13);
    PVSTEP(vc0, vc1, 14);
    PVSTEP(vd0, vd1, 15);

    float* og = out + ((size_t)(bh * S_LEN + qt * QT)) * D_DIM;
#pragma unroll
    for (int r = 0; r < 4; ++r) {
        const int row = quad * 4 + r;
        __builtin_nontemporal_store(oacc[r], &og[row * D_DIM + d0 + l15]);
    }
#undef SB
#undef LOADK
#undef QKSTEP
#undef LOADV
#undef PVSTEP
}

extern "C" void kernel_launch(void* const* d_in, const int* in_sizes, int n_in,
                              void* d_out, int out_size, void* d_ws, size_t ws_size,
                              hipStream_t stream)
{
    const float* q = (const float*)d_in[0];
    const float* k = (const float*)d_in[1];
    const float* v = (const float*)d_in[2];
    const float* sim = (const float*)d_in[3];
    const void* mask = d_in[4];
    float* out = (float*)d_out;
    float* attn = out + (size_t)4 * 16 * 1024 * 64;   // output first, then attn

    char* ws = (char*)d_ws;                           // needs 28 MB
    unsigned short* Qb = (unsigned short*)(ws + (size_t)0);
    unsigned short* Kb = (unsigned short*)(ws + ((size_t)8 << 20));
    unsigned short* Vt = (unsigned short*)(ws + ((size_t)16 << 20));
    unsigned char*  Mb = (unsigned char*)(ws + ((size_t)24 << 20));

    prep_qkm<<<4096, 256, 0, stream>>>(q, k, mask, Qb, Kb, Mb);
    prep_vt<<<1024, 256, 0, stream>>>(v, Vt);
    attn_main<<<4096, 256, 0, stream>>>(sim, Qb, Kb, Vt, Mb, out, attn);
}